// Round 14
// baseline (472.707 us; speedup 1.0000x reference)
//
#include <hip/hip_runtime.h>
#include <hip/hip_bf16.h>
#include <cstdint>

#define N_SAMP 8192
#define IN_DIM 1024
#define HID    2048
#define NE     4

typedef __attribute__((ext_vector_type(8))) __bf16 bf16x8;
typedef __attribute__((ext_vector_type(4))) float  f32x4;

#define MFMA16 __builtin_amdgcn_mfma_f32_16x16x32_bf16

__device__ __forceinline__ unsigned short f2b(float f) {
    unsigned u = __float_as_uint(f);
    u += 0x7fff + ((u >> 16) & 1);          // RNE, finite inputs only
    return (unsigned short)(u >> 16);
}
__device__ __forceinline__ float b2f(unsigned short s) {
    return __uint_as_float(((unsigned)s) << 16);
}

// async global->LDS, 16B per lane; LDS dest is wave-uniform base (+lane*16 by HW)
__device__ __forceinline__ void gll16(const void* g, void* l) {
    __builtin_amdgcn_global_load_lds(
        (const __attribute__((address_space(1))) void*)g,
        (__attribute__((address_space(3))) void*)l,
        16, 0, 0);
}

// LDS byte swizzle for 128B-row tiles: bits 4-6 ^= row bits 0-2 (byte bits 7-9).
// Involution; keeps 16B alignment; conflict-free ds_read_b128 (verified r6: conflicts=0).
__device__ __forceinline__ int swz(int byte) {
    return byte ^ (((byte >> 7) & 7) << 4);
}

// -------- transpose + convert: src [e][K][M] f32 -> dst [e][M][K] bf16 (z-batched) --------
__global__ void transpose_conv(const float* __restrict__ src, unsigned short* __restrict__ dst,
                               int K, int M, size_t srcStride, size_t dstStride) {
    __shared__ float tile[64][65];
    const int e  = blockIdx.z;
    const int k0 = blockIdx.x * 64, m0 = blockIdx.y * 64;
    const int t  = threadIdx.x;
    const int tc = t & 15, tr = t >> 4;
    const float* s = src + (size_t)e * srcStride + (size_t)k0 * M + m0;
    #pragma unroll
    for (int r = tr; r < 64; r += 16) {
        float4 v = *(const float4*)&s[(size_t)r * M + tc * 4];
        tile[r][tc * 4 + 0] = v.x; tile[r][tc * 4 + 1] = v.y;
        tile[r][tc * 4 + 2] = v.z; tile[r][tc * 4 + 3] = v.w;
    }
    __syncthreads();
    unsigned short* d = dst + (size_t)e * dstStride + (size_t)m0 * K + k0;
    #pragma unroll
    for (int r = tr; r < 64; r += 16) {
        ushort4 o;
        o.x = f2b(tile[tc * 4 + 0][r]); o.y = f2b(tile[tc * 4 + 1][r]);
        o.z = f2b(tile[tc * 4 + 2][r]); o.w = f2b(tile[tc * 4 + 3][r]);
        *(ushort4*)&d[(size_t)r * K + tc * 4] = o;
    }
}

// ------- router (fused with bf16 convert): fp32 logits, softmax, argmax, reg_loss -------
__global__ __launch_bounds__(256) void router_kernel(
    const float* __restrict__ bb, const int* __restrict__ task,
    const float* __restrict__ temb, const float* __restrict__ rm,
    unsigned short* __restrict__ Abf,
    float* __restrict__ gval, int* __restrict__ gidx,
    float* __restrict__ regout) {
    const int t = threadIdx.x, wave = t >> 6, lane = t & 63;
    const int n = blockIdx.x * 4 + wave;
    const int tk = task[n];
    float a0 = 0.f, a1 = 0.f, a2 = 0.f, a3 = 0.f;
    for (int i = lane; i < IN_DIM + 100; i += 64) {
        float x;
        if (i < IN_DIM) {
            x = bb[(size_t)n * IN_DIM + i];
            Abf[(size_t)n * IN_DIM + i] = f2b(x);
        } else {
            x = temb[tk * 100 + (i - IN_DIM)];
        }
        float4 r = *(const float4*)&rm[i * 4];
        a0 += x * r.x; a1 += x * r.y; a2 += x * r.z; a3 += x * r.w;
    }
    #pragma unroll
    for (int o = 32; o; o >>= 1) {
        a0 += __shfl_xor(a0, o); a1 += __shfl_xor(a1, o);
        a2 += __shfl_xor(a2, o); a3 += __shfl_xor(a3, o);
    }
    if (lane == 0) {
        float l[4] = {a0, a1, a2, a3};
        float mx = fmaxf(fmaxf(l[0], l[1]), fmaxf(l[2], l[3]));
        float ex[4], s = 0.f;
        #pragma unroll
        for (int j = 0; j < 4; j++) { ex[j] = expf(l[j] - mx); s += ex[j]; }
        int bi = 0; float bw = ex[0];
        #pragma unroll
        for (int j = 1; j < 4; j++) if (ex[j] > bw) { bw = ex[j]; bi = j; }
        float g = bw / s;
        gval[n] = g;
        gidx[n] = bi;
        regout[n] = -0.0025f * (logf(g + 1e-6f) + 3.0f * logf(1e-6f));
    }
}

// ---------------- per-expert compaction: list_e = {n : idx[n] >= e}; pad to mult 256 --------
__global__ void compact_kernel(const int* __restrict__ gidx, int* __restrict__ list,
                               int* __restrict__ pos, int* __restrict__ cnt) {
    const int e = blockIdx.x;
    const int t = threadIdx.x, lane = t & 63, wave = t >> 6;
    __shared__ int wbase[4];
    __shared__ int running;
    if (t == 0) running = 0;
    __syncthreads();
    int* le = list + (size_t)e * N_SAMP;
    int* pe = pos + (size_t)e * N_SAMP;
    for (int base = 0; base < N_SAMP; base += 256) {
        const int n = base + t;
        const bool f = gidx[n] >= e;
        unsigned long long m = __ballot(f);
        int rank = __popcll(m & ((1ULL << lane) - 1ULL));
        if (lane == 0) wbase[wave] = __popcll(m);
        __syncthreads();
        int wb = 0;
        #pragma unroll
        for (int w = 0; w < 4; w++) if (w < wave) wb += wbase[w];
        int tot = wbase[0] + wbase[1] + wbase[2] + wbase[3];
        int o = running + wb + rank;
        if (f) { le[o] = n; pe[n] = o; }
        __syncthreads();
        if (t == 0) running += tot;
        __syncthreads();
    }
    const int c = running;
    if (t == 0) cnt[e] = c;
    const int padded = (c + 255) & ~255;
    for (int i = c + t; i < padded && i < N_SAMP; i += 256) le[i] = 0;
}

// ================= 256x256 8-phase bf16 MFMA GEMM core (KT = compile-time K) =================
// REVERTED to the race-free r12 4-phase schedule (r13's 2-subphase merge raced:
// ds_reads could be in flight at the barrier while stages overwrote their region;
// it also gained ~0 perf). Every stage here is placed strictly AFTER the consuming
// MFMA of its LDS region (compiler lgkmcnt drain) + a barrier.
template<int KT>
__device__ __forceinline__ void gemm_core(
    const unsigned short* __restrict__ A, const unsigned short* __restrict__ BT,
    const float* __restrict__ bias, unsigned short* __restrict__ C,
    int M, const int* __restrict__ rowlist, const int* __restrict__ cntp,
    int bid, char* lds_) {
    constexpr int nt = KT / 64;
    const int cnt = *cntp;
    const int mb = bid & 7, nb = bid >> 3;
    const int n0 = nb * 256;
    if (n0 >= cnt) return;
    const int m0 = mb * 256;
    const int t = threadIdx.x;
    const int w = t >> 6, lane = t & 63;
    const int wm = w >> 2, wn = w & 3;          // wave -> (sample-half, m-quarter)
    const int lrow = lane & 15, kg = lane >> 4;

    int rr[2], cb[2];
    #pragma unroll
    for (int q = 0; q < 2; q++) {
        int Ps = swz((t + q * 512) * 16);
        rr[q] = Ps >> 7;
        cb[q] = Ps & 127;
    }
    const char* aS[2][2];
    const char* bS[2][2];
    #pragma unroll
    for (int h = 0; h < 2; h++)
        #pragma unroll
        for (int q = 0; q < 2; q++) {
            int r = n0 + h * 128 + rr[q];
            int ga = rowlist ? rowlist[r] : r;
            aS[h][q] = (const char*)A + (size_t)ga * (KT * 2) + cb[q];
            bS[h][q] = (const char*)BT + (size_t)(m0 + h * 128 + rr[q]) * (KT * 2) + cb[q];
        }

    auto stageA = [&](int buf, int h, int kt) {
        gll16(aS[h][0] + kt * 128, lds_ + buf * 65536 + h * 16384 + w * 1024);
        gll16(aS[h][1] + kt * 128, lds_ + buf * 65536 + h * 16384 + 8192 + w * 1024);
    };
    auto stageB = [&](int buf, int h, int kt) {
        gll16(bS[h][0] + kt * 128, lds_ + buf * 65536 + 32768 + h * 16384 + w * 1024);
        gll16(bS[h][1] + kt * 128, lds_ + buf * 65536 + 32768 + h * 16384 + 8192 + w * 1024);
    };

    const int mask = (lrow & 7) << 4;
    const int c0 = (kg * 16) ^ mask;
    const int c1 = (kg * 16 + 64) ^ mask;
    const char* const pA[2] = { lds_ + wm * 16384 + lrow * 128 + c0,
                                lds_ + wm * 16384 + lrow * 128 + c1 };
    const int browB = (wn & 1) * 64 + lrow;
    const char* const pB[2] = { lds_ + 32768 + (wn >> 1) * 16384 + browB * 128 + c0,
                                lds_ + 32768 + (wn >> 1) * 16384 + browB * 128 + c1 };
    auto ldA = [&](int buf, int i, int kk) -> bf16x8 {
        return *(const bf16x8*)(pA[kk] + buf * 65536 + i * 2048);
    };
    auto ldB = [&](int buf, int j, int kk) -> bf16x8 {
        return *(const bf16x8*)(pB[kk] + buf * 65536 + j * 2048);
    };

    f32x4 acc[8][4];
    #pragma unroll
    for (int i = 0; i < 8; i++)
        #pragma unroll
        for (int j = 0; j < 4; j++) acc[i][j] = (f32x4){0.f, 0.f, 0.f, 0.f};

    stageA(0, 0, 0); stageA(0, 1, 0); stageB(0, 0, 0); stageB(0, 1, 0);
    stageA(1, 0, 1); stageA(1, 1, 1); stageB(1, 0, 1);
    asm volatile("s_waitcnt vmcnt(6)" ::: "memory");
    __builtin_amdgcn_s_barrier();

    bf16x8 af[4][2], bfr[4][2];
    auto tile = [&](int kt, int buf) {
        // ---- phase 0: i0-3 x j0-1 (12 ds_reads); stage B1(t+1) -> buf^1
        #pragma unroll
        for (int i = 0; i < 4; i++) { af[i][0] = ldA(buf, i, 0); af[i][1] = ldA(buf, i, 1); }
        #pragma unroll
        for (int j = 0; j < 2; j++) { bfr[j][0] = ldB(buf, j, 0); bfr[j][1] = ldB(buf, j, 1); }
        if (kt + 1 < nt) stageB(buf ^ 1, 1, kt + 1);
        __builtin_amdgcn_s_barrier();
        __builtin_amdgcn_s_setprio(1);
        #pragma unroll
        for (int i = 0; i < 4; i++)
            #pragma unroll
            for (int j = 0; j < 2; j++) {
                acc[i][j] = MFMA16(af[i][0], bfr[j][0], acc[i][j], 0, 0, 0);
                acc[i][j] = MFMA16(af[i][1], bfr[j][1], acc[i][j], 0, 0, 0);
            }
        __builtin_amdgcn_s_setprio(0);
        __builtin_amdgcn_s_barrier();
        // ---- phase 1: i0-3 x j2-3 (4 ds_reads)
        #pragma unroll
        for (int j = 2; j < 4; j++) { bfr[j][0] = ldB(buf, j, 0); bfr[j][1] = ldB(buf, j, 1); }
        __builtin_amdgcn_s_barrier();
        __builtin_amdgcn_s_setprio(1);
        #pragma unroll
        for (int i = 0; i < 4; i++)
            #pragma unroll
            for (int j = 0; j < 2; j++) {
                acc[i][2 + j] = MFMA16(af[i][0], bfr[2 + j][0], acc[i][2 + j], 0, 0, 0);
                acc[i][2 + j] = MFMA16(af[i][1], bfr[2 + j][1], acc[i][2 + j], 0, 0, 0);
            }
        __builtin_amdgcn_s_setprio(0);
        __builtin_amdgcn_s_barrier();
        // ---- phase 2: i4-7 x j0-1 (8 ds_reads, af reused); stage B0(t+2) -> buf
        #pragma unroll
        for (int i = 0; i < 4; i++) { af[i][0] = ldA(buf, 4 + i, 0); af[i][1] = ldA(buf, 4 + i, 1); }
        if (kt + 2 < nt) stageB(buf, 0, kt + 2);
        __builtin_amdgcn_s_barrier();
        __builtin_amdgcn_s_setprio(1);
        #pragma unroll
        for (int i = 0; i < 4; i++)
            #pragma unroll
            for (int j = 0; j < 2; j++) {
                acc[4 + i][j] = MFMA16(af[i][0], bfr[j][0], acc[4 + i][j], 0, 0, 0);
                acc[4 + i][j] = MFMA16(af[i][1], bfr[j][1], acc[4 + i][j], 0, 0, 0);
            }
        __builtin_amdgcn_s_setprio(0);
        __builtin_amdgcn_s_barrier();
        // ---- phase 3: i4-7 x j2-3 (0 ds_reads); stage A0,A1(t+2) -> buf
        if (kt + 2 < nt) { stageA(buf, 0, kt + 2); stageA(buf, 1, kt + 2); }
        __builtin_amdgcn_s_barrier();
        __builtin_amdgcn_s_setprio(1);
        #pragma unroll
        for (int i = 0; i < 4; i++)
            #pragma unroll
            for (int j = 0; j < 2; j++) {
                acc[4 + i][2 + j] = MFMA16(af[i][0], bfr[2 + j][0], acc[4 + i][2 + j], 0, 0, 0);
                acc[4 + i][2 + j] = MFMA16(af[i][1], bfr[2 + j][1], acc[4 + i][2 + j], 0, 0, 0);
            }
        __builtin_amdgcn_s_setprio(0);
        if (kt < nt - 2) asm volatile("s_waitcnt vmcnt(6)" ::: "memory");
        else             asm volatile("s_waitcnt vmcnt(0)" ::: "memory");
        __builtin_amdgcn_s_barrier();
    };
    for (int kt = 0; kt < nt; kt += 2) { tile(kt, 0); tile(kt + 1, 1); }

    // epilogue: C/D layout col=lane&15, row=(lane>>4)*4+q  (m89-verified)
    float bv[4];
    #pragma unroll
    for (int j = 0; j < 4; j++)
        bv[j] = bias[m0 + wn * 64 + j * 16 + lrow];
    #pragma unroll
    for (int i = 0; i < 8; i++) {
        const int srow0 = n0 + wm * 128 + i * 16 + kg * 4;
        #pragma unroll
        for (int j = 0; j < 4; j++) {
            const int col = m0 + wn * 64 + j * 16 + lrow;
            #pragma unroll
            for (int q = 0; q < 4; q++) {
                if (srow0 + q < cnt) {
                    float x = acc[i][j][q] + bv[j];
                    C[(size_t)(srow0 + q) * M + col] = f2b(fmaxf(x, 0.f));
                }
            }
        }
    }
}

template<int KT>
__global__ __launch_bounds__(512, 2) void gemm256(
    const unsigned short* __restrict__ A, const unsigned short* __restrict__ BT,
    const float* __restrict__ bias, unsigned short* __restrict__ C,
    int M, const int* __restrict__ rowlist, const int* __restrict__ cntp) {
    extern __shared__ char lds_[];
    gemm_core<KT>(A, BT, bias, C, M, rowlist, cntp, blockIdx.x, lds_);
}

// packed: bids [0,256) = G2 (K=HID);  bids [256,512) = G1 (K=IN_DIM)
__global__ __launch_bounds__(512, 2) void gemm256_dual(
    const unsigned short* __restrict__ A2, const unsigned short* __restrict__ BT2,
    const float* __restrict__ bias2, unsigned short* __restrict__ C2,
    const int* __restrict__ cnt2,
    const unsigned short* __restrict__ A1, const unsigned short* __restrict__ BT1,
    const float* __restrict__ bias1, unsigned short* __restrict__ C1,
    const int* __restrict__ rowlist1, const int* __restrict__ cnt1) {
    extern __shared__ char lds_[];
    const int bid = blockIdx.x;
    if (bid < 256) {
        gemm_core<HID>(A2, BT2, bias2, C2, HID, nullptr, cnt2, bid, lds_);
    } else {
        gemm_core<IN_DIM>(A1, BT1, bias1, C1, HID, rowlist1, cnt1, bid - 256, lds_);
    }
}

// packed: two G1 jobs (both K=IN_DIM, shared A)
__global__ __launch_bounds__(512, 2) void gemm256_dual_g1g1(
    const unsigned short* __restrict__ A,
    const unsigned short* __restrict__ BTa, const float* __restrict__ biasa,
    unsigned short* __restrict__ Ca, const int* __restrict__ rla, const int* __restrict__ cnta,
    const unsigned short* __restrict__ BTb, const float* __restrict__ biasb,
    unsigned short* __restrict__ Cb, const int* __restrict__ rlb, const int* __restrict__ cntb) {
    extern __shared__ char lds_[];
    const int bid = blockIdx.x;
    if (bid < 256) {
        gemm_core<IN_DIM>(A, BTa, biasa, Ca, HID, rla, cnta, bid, lds_);
    } else {
        gemm_core<IN_DIM>(A, BTb, biasb, Cb, HID, rlb, cntb, bid - 256, lds_);
    }
}

// packed: two G2 jobs (both K=HID)
__global__ __launch_bounds__(512, 2) void gemm256_dual_g2g2(
    const unsigned short* __restrict__ Aa, const unsigned short* __restrict__ BTa,
    const float* __restrict__ biasa, unsigned short* __restrict__ Ca, const int* __restrict__ cnta,
    const unsigned short* __restrict__ Ab, const unsigned short* __restrict__ BTb,
    const float* __restrict__ biasb, unsigned short* __restrict__ Cb, const int* __restrict__ cntb) {
    extern __shared__ char lds_[];
    const int bid = blockIdx.x;
    if (bid < 256) {
        gemm_core<HID>(Aa, BTa, biasa, Ca, HID, nullptr, cnta, bid, lds_);
    } else {
        gemm_core<HID>(Ab, BTb, biasb, Cb, HID, nullptr, cntb, bid - 256, lds_);
    }
}

// ---------------- Gram-Schmidt + gather: one wave per sample (compact obf via pos) ------------
__global__ __launch_bounds__(256, 1) void gs_kernel(
    const unsigned short* __restrict__ eo, const float* __restrict__ gval,
    const int* __restrict__ gidx, const int* __restrict__ pos,
    float* __restrict__ dout) {
    const int t = threadIdx.x, wave = t >> 6, lane = t & 63;
    const int n = blockIdx.x * 4 + wave;
    const int idx = gidx[n];
    const float g = gval[n];

    float v[32], b0[32], b1[32], b2[32];

    auto loadv = [&](float* dst, int e) {
        const size_t row = pos[(size_t)e * N_SAMP + n];
        const unsigned short* p = eo + ((size_t)e * N_SAMP + row) * HID + lane * 8;
        #pragma unroll
        for (int c = 0; c < 4; c++) {
            uint4 u = *(const uint4*)(p + c * 512);
            const unsigned short* us = (const unsigned short*)&u;
            #pragma unroll
            for (int j = 0; j < 8; j++) dst[c * 8 + j] = b2f(us[j]);
        }
    };
    auto wdot = [&](const float* x, const float* y) -> float {
        float s = 0.f;
        #pragma unroll
        for (int k = 0; k < 32; k++) s += x[k] * y[k];
        #pragma unroll
        for (int o = 32; o; o >>= 1) s += __shfl_xor(s, o);
        return s;
    };
    auto storev = [&](const float* b) {
        float* o = dout + (size_t)n * HID + lane * 8;
        #pragma unroll
        for (int c = 0; c < 4; c++) {
            float4 x0, x1;
            x0.x = g * b[c * 8 + 0]; x0.y = g * b[c * 8 + 1];
            x0.z = g * b[c * 8 + 2]; x0.w = g * b[c * 8 + 3];
            x1.x = g * b[c * 8 + 4]; x1.y = g * b[c * 8 + 5];
            x1.z = g * b[c * 8 + 6]; x1.w = g * b[c * 8 + 7];
            *(float4*)(o + c * 512) = x0;
            *(float4*)(o + c * 512 + 4) = x1;
        }
    };

    loadv(v, 0);
    float inv = 1.f / sqrtf(wdot(v, v));
    #pragma unroll
    for (int k = 0; k < 32; k++) b0[k] = v[k] * inv;
    if (idx == 0) { storev(b0); return; }
    loadv(v, 1);
    {
        float cc0 = wdot(v, b0);
        #pragma unroll
        for (int k = 0; k < 32; k++) v[k] -= cc0 * b0[k];
        inv = 1.f / sqrtf(wdot(v, v));
        #pragma unroll
        for (int k = 0; k < 32; k++) b1[k] = v[k] * inv;
    }
    if (idx == 1) { storev(b1); return; }
    loadv(v, 2);
    {
        float cc0 = wdot(v, b0);
        float cc1 = wdot(v, b1);
        #pragma unroll
        for (int k = 0; k < 32; k++) v[k] -= cc0 * b0[k] + cc1 * b1[k];
        inv = 1.f / sqrtf(wdot(v, v));
        #pragma unroll
        for (int k = 0; k < 32; k++) b2[k] = v[k] * inv;
    }
    if (idx == 2) { storev(b2); return; }
    loadv(v, 3);
    {
        float cc0 = wdot(v, b0);
        float cc1 = wdot(v, b1);
        float cc2 = wdot(v, b2);
        #pragma unroll
        for (int k = 0; k < 32; k++) v[k] -= cc0 * b0[k] + cc1 * b1[k] + cc2 * b2[k];
        inv = 1.f / sqrtf(wdot(v, v));
        #pragma unroll
        for (int k = 0; k < 32; k++) v[k] *= inv;
    }
    storev(v);
}

extern "C" void kernel_launch(void* const* d_in, const int* in_sizes, int n_in,
                              void* d_out, int out_size, void* d_ws, size_t ws_size,
                              hipStream_t stream) {
    const float* bb   = (const float*)d_in[0];
    const int*   task = (const int*)d_in[1];
    const float* temb = (const float*)d_in[2];
    const float* rm   = (const float*)d_in[3];
    const float* W1   = (const float*)d_in[4];
    const float* b1   = (const float*)d_in[5];
    const float* W2   = (const float*)d_in[6];
    const float* b2   = (const float*)d_in[7];
    float* out = (float*)d_out;
    char* ws = (char*)d_ws;

    const size_t lds_bytes = 131072;
    const size_t W1S = (size_t)IN_DIM * HID;   // W1T expert stride (elements)
    const size_t W2S = (size_t)HID * HID;      // W2T expert stride (elements)
    const size_t NEED_C = 251986176;           // plan C: fully batched transposes
    const size_t NEED_B = 243597376;           // plan B: proven bound (r10/r11)

    if (ws_size >= NEED_B) {
        const bool planC = (ws_size >= NEED_C);
        unsigned short* obf  = (unsigned short*)(ws + 0);           // 128 MB [E][N][HID]
        unsigned short* h0   = (unsigned short*)(ws + 33554432);    // = obf[1] slot
        unsigned short* h1   = (unsigned short*)(ws + 67108864);    // = obf[2] slot
        unsigned short* Abf  = (unsigned short*)(ws + 134217728);   // 16 MB (dead after D2)
        unsigned short* h2   = (unsigned short*)(ws + 150994944);   // 32 MB
        unsigned short* h3   = (unsigned short*)(ws + 184549376);   // 32 MB
        unsigned short* W1T  = (unsigned short*)(ws + 218103808);   // 16 MB: all 4 experts
        unsigned short* W2T  = (unsigned short*)(ws + 234881024);   // C: 16 MB (e0,e1); B: 8 MB single
        unsigned short* W2T23 = Abf;                                // W2T(2),(3) land in dead Abf
        const size_t smallOfs = planC ? 251658240u : 243269632u;
        float* gv   = (float*)(ws + smallOfs);
        int*   gi   = (int*)(ws + smallOfs + 32768);
        int*   list = (int*)(ws + smallOfs + 65536);
        int*   pos  = (int*)(ws + smallOfs + 196608);
        int*   cnt  = (int*)(ws + smallOfs + 327680);

        router_kernel<<<N_SAMP / 4, 256, 0, stream>>>(bb, task, temb, rm, Abf, gv, gi,
                                                      out + (size_t)N_SAMP * HID);
        compact_kernel<<<NE, 256, 0, stream>>>(gi, list, pos, cnt);

        transpose_conv<<<dim3(IN_DIM / 64, HID / 64, NE), 256, 0, stream>>>(
            W1, W1T, IN_DIM, HID, W1S, W1S);
        if (planC) {
            transpose_conv<<<dim3(HID / 64, HID / 64, 2), 256, 0, stream>>>(
                W2, W2T, HID, HID, W2S, W2S);
        } else {
            transpose_conv<<<dim3(HID / 64, HID / 64, 1), 256, 0, stream>>>(
                W2, W2T, HID, HID, 0, 0);
        }

        // D0: [G1(0)->h0 | G1(1)->h1]
        gemm256_dual_g1g1<<<512, 512, lds_bytes, stream>>>(
            Abf, W1T, b1, h0, list, cnt,
            W1T + W1S, b1 + HID, h1, list + N_SAMP, cnt + 1);

        // D1: [G2(0): h0 -> obf0 | G1(2) -> h2]
        gemm256_dual<<<512, 512, lds_bytes, stream>>>(
            h0, W2T, b2, obf, cnt,
            Abf, W1T + 2 * W1S, b1 + 2 * HID, h2, list + (size_t)2 * N_SAMP, cnt + 2);

        if (!planC) {
            transpose_conv<<<dim3(HID / 64, HID / 64, 1), 256, 0, stream>>>(
                W2 + W2S, W2T, HID, HID, 0, 0);
        }
        const unsigned short* W2T1 = planC ? (W2T + W2S) : W2T;

        // D2: [G2(1): h1 -> obf1 | G1(3) -> h3]
        gemm256_dual<<<512, 512, lds_bytes, stream>>>(
            h1, W2T1, b2 + HID, obf + (size_t)1 * N_SAMP * HID, cnt + 1,
            Abf, W1T + 3 * W1S, b1 + 3 * HID, h3, list + (size_t)3 * N_SAMP, cnt + 3);

        // W2T(2),(3) -> dead Abf region (Abf's last read was G1(3) in D2)
        transpose_conv<<<dim3(HID / 64, HID / 64, 2), 256, 0, stream>>>(
            W2 + 2 * W2S, W2T23, HID, HID, W2S, W2S);

        // D3: [G2(2): h2 -> obf2 | G2(3): h3 -> obf3]
        gemm256_dual_g2g2<<<512, 512, lds_bytes, stream>>>(
            h2, W2T23, b2 + 2 * HID, obf + (size_t)2 * N_SAMP * HID, cnt + 2,
            h3, W2T23 + W2S, b2 + 3 * HID, obf + (size_t)3 * N_SAMP * HID, cnt + 3);

        gs_kernel<<<N_SAMP / 4, 256, 0, stream>>>(obf, gv, gi, pos, out);
    } else {
        // ===== fallback: round-9 structure, ~197.5 MB (proven) =====
        unsigned short* obf  = (unsigned short*)(ws + 0);
        unsigned short* Abf  = (unsigned short*)(ws + 134217728);
        unsigned short* hbfA = (unsigned short*)(ws + 150994944);
        unsigned short* W1T  = (unsigned short*)(ws + 184549376);
        unsigned short* W2T  = (unsigned short*)(ws + 188743680);
        float*          gv   = (float*)(ws + 197132288);
        int*            gi   = (int*)(ws + 197165056);
        int*            list = (int*)(ws + 197197824);
        int*            pos  = (int*)(ws + 197328896);
        int*            cnt  = (int*)(ws + 197459968);
        unsigned short* hbfB = obf + (size_t)3 * N_SAMP * HID;
        auto hbf = [&](int e) { return (e & 1) ? hbfA : hbfB; };

        router_kernel<<<N_SAMP / 4, 256, 0, stream>>>(bb, task, temb, rm, Abf, gv, gi,
                                                      out + (size_t)N_SAMP * HID);
        compact_kernel<<<NE, 256, 0, stream>>>(gi, list, pos, cnt);

        transpose_conv<<<dim3(IN_DIM / 64, HID / 64, 1), 256, 0, stream>>>(
            W1, W1T, IN_DIM, HID, 0, 0);
        gemm256<IN_DIM><<<256, 512, lds_bytes, stream>>>(
            Abf, W1T, b1, hbf(0), HID, list, cnt);

        for (int e = 0; e < 3; ++e) {
            transpose_conv<<<dim3(HID / 64, HID / 64, 1), 256, 0, stream>>>(
                W2 + (size_t)e * W2S, W2T, HID, HID, 0, 0);
            transpose_conv<<<dim3(IN_DIM / 64, HID / 64, 1), 256, 0, stream>>>(
                W1 + (size_t)(e + 1) * W1S, W1T, IN_DIM, HID, 0, 0);
            gemm256_dual<<<512, 512, lds_bytes, stream>>>(
                hbf(e), W2T, b2 + (size_t)e * HID, obf + (size_t)e * N_SAMP * HID, cnt + e,
                Abf, W1T, b1 + (size_t)(e + 1) * HID, hbf(e + 1),
                list + (size_t)(e + 1) * N_SAMP, cnt + e + 1);
        }

        transpose_conv<<<dim3(HID / 64, HID / 64, 1), 256, 0, stream>>>(
            W2 + (size_t)3 * W2S, W2T, HID, HID, 0, 0);
        gemm256<HID><<<256, 512, lds_bytes, stream>>>(
            hbf(3), W2T, b2 + (size_t)3 * HID, obf + (size_t)3 * N_SAMP * HID, HID,
            nullptr, cnt + 3);

        gs_kernel<<<N_SAMP / 4, 256, 0, stream>>>(obf, gv, gi, pos, out);
    }
}

// Round 15
// 472.599 us; speedup vs baseline: 1.0002x; 1.0002x over previous
//
#include <hip/hip_runtime.h>
#include <hip/hip_bf16.h>
#include <cstdint>

#define N_SAMP 8192
#define IN_DIM 1024
#define HID    2048
#define NE     4

typedef __attribute__((ext_vector_type(8))) __bf16 bf16x8;
typedef __attribute__((ext_vector_type(4))) float  f32x4;

#define MFMA16 __builtin_amdgcn_mfma_f32_16x16x32_bf16

__device__ __forceinline__ unsigned short f2b(float f) {
    unsigned u = __float_as_uint(f);
    u += 0x7fff + ((u >> 16) & 1);          // RNE, finite inputs only
    return (unsigned short)(u >> 16);
}
__device__ __forceinline__ float b2f(unsigned short s) {
    return __uint_as_float(((unsigned)s) << 16);
}

// async global->LDS, 16B per lane; LDS dest is wave-uniform base (+lane*16 by HW)
__device__ __forceinline__ void gll16(const void* g, void* l) {
    __builtin_amdgcn_global_load_lds(
        (const __attribute__((address_space(1))) void*)g,
        (__attribute__((address_space(3))) void*)l,
        16, 0, 0);
}

// LDS byte swizzle for 128B-row tiles: bits 4-6 ^= row bits 0-2 (byte bits 7-9).
// Involution; keeps 16B alignment; conflict-free ds_read_b128 (verified r6: conflicts=0).
__device__ __forceinline__ int swz(int byte) {
    return byte ^ (((byte >> 7) & 7) << 4);
}

// -------- transpose + convert: src [e][K][M] f32 -> dst [e][M][K] bf16 (z-batched) --------
__global__ void transpose_conv(const float* __restrict__ src, unsigned short* __restrict__ dst,
                               int K, int M, size_t srcStride, size_t dstStride) {
    __shared__ float tile[64][65];
    const int e  = blockIdx.z;
    const int k0 = blockIdx.x * 64, m0 = blockIdx.y * 64;
    const int t  = threadIdx.x;
    const int tc = t & 15, tr = t >> 4;
    const float* s = src + (size_t)e * srcStride + (size_t)k0 * M + m0;
    #pragma unroll
    for (int r = tr; r < 64; r += 16) {
        float4 v = *(const float4*)&s[(size_t)r * M + tc * 4];
        tile[r][tc * 4 + 0] = v.x; tile[r][tc * 4 + 1] = v.y;
        tile[r][tc * 4 + 2] = v.z; tile[r][tc * 4 + 3] = v.w;
    }
    __syncthreads();
    unsigned short* d = dst + (size_t)e * dstStride + (size_t)m0 * K + k0;
    #pragma unroll
    for (int r = tr; r < 64; r += 16) {
        ushort4 o;
        o.x = f2b(tile[tc * 4 + 0][r]); o.y = f2b(tile[tc * 4 + 1][r]);
        o.z = f2b(tile[tc * 4 + 2][r]); o.w = f2b(tile[tc * 4 + 3][r]);
        *(ushort4*)&d[(size_t)r * K + tc * 4] = o;
    }
}

// ------- router (fused with bf16 convert): fp32 logits, softmax, argmax, reg_loss -------
__global__ __launch_bounds__(256) void router_kernel(
    const float* __restrict__ bb, const int* __restrict__ task,
    const float* __restrict__ temb, const float* __restrict__ rm,
    unsigned short* __restrict__ Abf,
    float* __restrict__ gval, int* __restrict__ gidx,
    float* __restrict__ regout) {
    const int t = threadIdx.x, wave = t >> 6, lane = t & 63;
    const int n = blockIdx.x * 4 + wave;
    const int tk = task[n];
    float a0 = 0.f, a1 = 0.f, a2 = 0.f, a3 = 0.f;
    for (int i = lane; i < IN_DIM + 100; i += 64) {
        float x;
        if (i < IN_DIM) {
            x = bb[(size_t)n * IN_DIM + i];
            Abf[(size_t)n * IN_DIM + i] = f2b(x);
        } else {
            x = temb[tk * 100 + (i - IN_DIM)];
        }
        float4 r = *(const float4*)&rm[i * 4];
        a0 += x * r.x; a1 += x * r.y; a2 += x * r.z; a3 += x * r.w;
    }
    #pragma unroll
    for (int o = 32; o; o >>= 1) {
        a0 += __shfl_xor(a0, o); a1 += __shfl_xor(a1, o);
        a2 += __shfl_xor(a2, o); a3 += __shfl_xor(a3, o);
    }
    if (lane == 0) {
        float l[4] = {a0, a1, a2, a3};
        float mx = fmaxf(fmaxf(l[0], l[1]), fmaxf(l[2], l[3]));
        float ex[4], s = 0.f;
        #pragma unroll
        for (int j = 0; j < 4; j++) { ex[j] = expf(l[j] - mx); s += ex[j]; }
        int bi = 0; float bw = ex[0];
        #pragma unroll
        for (int j = 1; j < 4; j++) if (ex[j] > bw) { bw = ex[j]; bi = j; }
        float g = bw / s;
        gval[n] = g;
        gidx[n] = bi;
        regout[n] = -0.0025f * (logf(g + 1e-6f) + 3.0f * logf(1e-6f));
    }
}

// ---------------- per-expert compaction: list_e = {n : idx[n] >= e}; pad to mult 256 --------
__global__ void compact_kernel(const int* __restrict__ gidx, int* __restrict__ list,
                               int* __restrict__ pos, int* __restrict__ cnt) {
    const int e = blockIdx.x;
    const int t = threadIdx.x, lane = t & 63, wave = t >> 6;
    __shared__ int wbase[4];
    __shared__ int running;
    if (t == 0) running = 0;
    __syncthreads();
    int* le = list + (size_t)e * N_SAMP;
    int* pe = pos + (size_t)e * N_SAMP;
    for (int base = 0; base < N_SAMP; base += 256) {
        const int n = base + t;
        const bool f = gidx[n] >= e;
        unsigned long long m = __ballot(f);
        int rank = __popcll(m & ((1ULL << lane) - 1ULL));
        if (lane == 0) wbase[wave] = __popcll(m);
        __syncthreads();
        int wb = 0;
        #pragma unroll
        for (int w = 0; w < 4; w++) if (w < wave) wb += wbase[w];
        int tot = wbase[0] + wbase[1] + wbase[2] + wbase[3];
        int o = running + wb + rank;
        if (f) { le[o] = n; pe[n] = o; }
        __syncthreads();
        if (t == 0) running += tot;
        __syncthreads();
    }
    const int c = running;
    if (t == 0) cnt[e] = c;
    const int padded = (c + 255) & ~255;
    for (int i = c + t; i < padded && i < N_SAMP; i += 256) le[i] = 0;
}

// ================= 256x256 8-phase bf16 MFMA GEMM core (KT = compile-time K) =================
// Race-free r12/r14 4-phase schedule. nbOff shifts the n-block range (for split jobs);
// all full-grid call sites pass 0 (constant-folded).
template<int KT>
__device__ __forceinline__ void gemm_core(
    const unsigned short* __restrict__ A, const unsigned short* __restrict__ BT,
    const float* __restrict__ bias, unsigned short* __restrict__ C,
    int M, const int* __restrict__ rowlist, const int* __restrict__ cntp,
    int bid, int nbOff, char* lds_) {
    constexpr int nt = KT / 64;
    const int cnt = *cntp;
    const int mb = bid & 7, nb = (bid >> 3) + nbOff;
    const int n0 = nb * 256;
    if (n0 >= cnt) return;
    const int m0 = mb * 256;
    const int t = threadIdx.x;
    const int w = t >> 6, lane = t & 63;
    const int wm = w >> 2, wn = w & 3;          // wave -> (sample-half, m-quarter)
    const int lrow = lane & 15, kg = lane >> 4;

    int rr[2], cb[2];
    #pragma unroll
    for (int q = 0; q < 2; q++) {
        int Ps = swz((t + q * 512) * 16);
        rr[q] = Ps >> 7;
        cb[q] = Ps & 127;
    }
    const char* aS[2][2];
    const char* bS[2][2];
    #pragma unroll
    for (int h = 0; h < 2; h++)
        #pragma unroll
        for (int q = 0; q < 2; q++) {
            int r = n0 + h * 128 + rr[q];
            int ga = rowlist ? rowlist[r] : r;
            aS[h][q] = (const char*)A + (size_t)ga * (KT * 2) + cb[q];
            bS[h][q] = (const char*)BT + (size_t)(m0 + h * 128 + rr[q]) * (KT * 2) + cb[q];
        }

    auto stageA = [&](int buf, int h, int kt) {
        gll16(aS[h][0] + kt * 128, lds_ + buf * 65536 + h * 16384 + w * 1024);
        gll16(aS[h][1] + kt * 128, lds_ + buf * 65536 + h * 16384 + 8192 + w * 1024);
    };
    auto stageB = [&](int buf, int h, int kt) {
        gll16(bS[h][0] + kt * 128, lds_ + buf * 65536 + 32768 + h * 16384 + w * 1024);
        gll16(bS[h][1] + kt * 128, lds_ + buf * 65536 + 32768 + h * 16384 + 8192 + w * 1024);
    };

    const int mask = (lrow & 7) << 4;
    const int c0 = (kg * 16) ^ mask;
    const int c1 = (kg * 16 + 64) ^ mask;
    const char* const pA[2] = { lds_ + wm * 16384 + lrow * 128 + c0,
                                lds_ + wm * 16384 + lrow * 128 + c1 };
    const int browB = (wn & 1) * 64 + lrow;
    const char* const pB[2] = { lds_ + 32768 + (wn >> 1) * 16384 + browB * 128 + c0,
                                lds_ + 32768 + (wn >> 1) * 16384 + browB * 128 + c1 };
    auto ldA = [&](int buf, int i, int kk) -> bf16x8 {
        return *(const bf16x8*)(pA[kk] + buf * 65536 + i * 2048);
    };
    auto ldB = [&](int buf, int j, int kk) -> bf16x8 {
        return *(const bf16x8*)(pB[kk] + buf * 65536 + j * 2048);
    };

    f32x4 acc[8][4];
    #pragma unroll
    for (int i = 0; i < 8; i++)
        #pragma unroll
        for (int j = 0; j < 4; j++) acc[i][j] = (f32x4){0.f, 0.f, 0.f, 0.f};

    stageA(0, 0, 0); stageA(0, 1, 0); stageB(0, 0, 0); stageB(0, 1, 0);
    stageA(1, 0, 1); stageA(1, 1, 1); stageB(1, 0, 1);
    asm volatile("s_waitcnt vmcnt(6)" ::: "memory");
    __builtin_amdgcn_s_barrier();

    bf16x8 af[4][2], bfr[4][2];
    auto tile = [&](int kt, int buf) {
        // ---- phase 0: i0-3 x j0-1 (12 ds_reads); stage B1(t+1) -> buf^1
        #pragma unroll
        for (int i = 0; i < 4; i++) { af[i][0] = ldA(buf, i, 0); af[i][1] = ldA(buf, i, 1); }
        #pragma unroll
        for (int j = 0; j < 2; j++) { bfr[j][0] = ldB(buf, j, 0); bfr[j][1] = ldB(buf, j, 1); }
        if (kt + 1 < nt) stageB(buf ^ 1, 1, kt + 1);
        __builtin_amdgcn_s_barrier();
        __builtin_amdgcn_s_setprio(1);
        #pragma unroll
        for (int i = 0; i < 4; i++)
            #pragma unroll
            for (int j = 0; j < 2; j++) {
                acc[i][j] = MFMA16(af[i][0], bfr[j][0], acc[i][j], 0, 0, 0);
                acc[i][j] = MFMA16(af[i][1], bfr[j][1], acc[i][j], 0, 0, 0);
            }
        __builtin_amdgcn_s_setprio(0);
        __builtin_amdgcn_s_barrier();
        // ---- phase 1: i0-3 x j2-3 (4 ds_reads)
        #pragma unroll
        for (int j = 2; j < 4; j++) { bfr[j][0] = ldB(buf, j, 0); bfr[j][1] = ldB(buf, j, 1); }
        __builtin_amdgcn_s_barrier();
        __builtin_amdgcn_s_setprio(1);
        #pragma unroll
        for (int i = 0; i < 4; i++)
            #pragma unroll
            for (int j = 0; j < 2; j++) {
                acc[i][2 + j] = MFMA16(af[i][0], bfr[2 + j][0], acc[i][2 + j], 0, 0, 0);
                acc[i][2 + j] = MFMA16(af[i][1], bfr[2 + j][1], acc[i][2 + j], 0, 0, 0);
            }
        __builtin_amdgcn_s_setprio(0);
        __builtin_amdgcn_s_barrier();
        // ---- phase 2: i4-7 x j0-1 (8 ds_reads, af reused); stage B0(t+2) -> buf
        #pragma unroll
        for (int i = 0; i < 4; i++) { af[i][0] = ldA(buf, 4 + i, 0); af[i][1] = ldA(buf, 4 + i, 1); }
        if (kt + 2 < nt) stageB(buf, 0, kt + 2);
        __builtin_amdgcn_s_barrier();
        __builtin_amdgcn_s_setprio(1);
        #pragma unroll
        for (int i = 0; i < 4; i++)
            #pragma unroll
            for (int j = 0; j < 2; j++) {
                acc[4 + i][j] = MFMA16(af[i][0], bfr[j][0], acc[4 + i][j], 0, 0, 0);
                acc[4 + i][j] = MFMA16(af[i][1], bfr[j][1], acc[4 + i][j], 0, 0, 0);
            }
        __builtin_amdgcn_s_setprio(0);
        __builtin_amdgcn_s_barrier();
        // ---- phase 3: i4-7 x j2-3 (0 ds_reads); stage A0,A1(t+2) -> buf
        if (kt + 2 < nt) { stageA(buf, 0, kt + 2); stageA(buf, 1, kt + 2); }
        __builtin_amdgcn_s_barrier();
        __builtin_amdgcn_s_setprio(1);
        #pragma unroll
        for (int i = 0; i < 4; i++)
            #pragma unroll
            for (int j = 0; j < 2; j++) {
                acc[4 + i][2 + j] = MFMA16(af[i][0], bfr[2 + j][0], acc[4 + i][2 + j], 0, 0, 0);
                acc[4 + i][2 + j] = MFMA16(af[i][1], bfr[2 + j][1], acc[4 + i][2 + j], 0, 0, 0);
            }
        __builtin_amdgcn_s_setprio(0);
        if (kt < nt - 2) asm volatile("s_waitcnt vmcnt(6)" ::: "memory");
        else             asm volatile("s_waitcnt vmcnt(0)" ::: "memory");
        __builtin_amdgcn_s_barrier();
    };
    for (int kt = 0; kt < nt; kt += 2) { tile(kt, 0); tile(kt + 1, 1); }

    // epilogue: C/D layout col=lane&15, row=(lane>>4)*4+q  (m89-verified)
    float bv[4];
    #pragma unroll
    for (int j = 0; j < 4; j++)
        bv[j] = bias[m0 + wn * 64 + j * 16 + lrow];
    #pragma unroll
    for (int i = 0; i < 8; i++) {
        const int srow0 = n0 + wm * 128 + i * 16 + kg * 4;
        #pragma unroll
        for (int j = 0; j < 4; j++) {
            const int col = m0 + wn * 64 + j * 16 + lrow;
            #pragma unroll
            for (int q = 0; q < 4; q++) {
                if (srow0 + q < cnt) {
                    float x = acc[i][j][q] + bv[j];
                    C[(size_t)(srow0 + q) * M + col] = f2b(fmaxf(x, 0.f));
                }
            }
        }
    }
}

template<int KT>
__global__ __launch_bounds__(512, 2) void gemm256(
    const unsigned short* __restrict__ A, const unsigned short* __restrict__ BT,
    const float* __restrict__ bias, unsigned short* __restrict__ C,
    int M, const int* __restrict__ rowlist, const int* __restrict__ cntp) {
    extern __shared__ char lds_[];
    gemm_core<KT>(A, BT, bias, C, M, rowlist, cntp, blockIdx.x, 0, lds_);
}

// packed: bids [0,256) = G2 (K=HID);  bids [256,512) = G1 (K=IN_DIM)
__global__ __launch_bounds__(512, 2) void gemm256_dual(
    const unsigned short* __restrict__ A2, const unsigned short* __restrict__ BT2,
    const float* __restrict__ bias2, unsigned short* __restrict__ C2,
    const int* __restrict__ cnt2,
    const unsigned short* __restrict__ A1, const unsigned short* __restrict__ BT1,
    const float* __restrict__ bias1, unsigned short* __restrict__ C1,
    const int* __restrict__ rowlist1, const int* __restrict__ cnt1) {
    extern __shared__ char lds_[];
    const int bid = blockIdx.x;
    if (bid < 256) {
        gemm_core<HID>(A2, BT2, bias2, C2, HID, nullptr, cnt2, bid, 0, lds_);
    } else {
        gemm_core<IN_DIM>(A1, BT1, bias1, C1, HID, rowlist1, cnt1, bid - 256, 0, lds_);
    }
}

// packed: two G1 jobs (both K=IN_DIM, shared A)
__global__ __launch_bounds__(512, 2) void gemm256_dual_g1g1(
    const unsigned short* __restrict__ A,
    const unsigned short* __restrict__ BTa, const float* __restrict__ biasa,
    unsigned short* __restrict__ Ca, const int* __restrict__ rla, const int* __restrict__ cnta,
    const unsigned short* __restrict__ BTb, const float* __restrict__ biasb,
    unsigned short* __restrict__ Cb, const int* __restrict__ rlb, const int* __restrict__ cntb) {
    extern __shared__ char lds_[];
    const int bid = blockIdx.x;
    if (bid < 256) {
        gemm_core<IN_DIM>(A, BTa, biasa, Ca, HID, rla, cnta, bid, 0, lds_);
    } else {
        gemm_core<IN_DIM>(A, BTb, biasb, Cb, HID, rlb, cntb, bid - 256, 0, lds_);
    }
}

// packed: two G2 jobs (both K=HID)
__global__ __launch_bounds__(512, 2) void gemm256_dual_g2g2(
    const unsigned short* __restrict__ Aa, const unsigned short* __restrict__ BTa,
    const float* __restrict__ biasa, unsigned short* __restrict__ Ca, const int* __restrict__ cnta,
    const unsigned short* __restrict__ Ab, const unsigned short* __restrict__ BTb,
    const float* __restrict__ biasb, unsigned short* __restrict__ Cb, const int* __restrict__ cntb) {
    extern __shared__ char lds_[];
    const int bid = blockIdx.x;
    if (bid < 256) {
        gemm_core<HID>(Aa, BTa, biasa, Ca, HID, nullptr, cnta, bid, 0, lds_);
    } else {
        gemm_core<HID>(Ab, BTb, biasb, Cb, HID, nullptr, cntb, bid - 256, 0, lds_);
    }
}

// ===== plan-E packed wrappers (n-split G2 jobs; all segment bases multiples of 8) =====
// D1: [G2(0) n0..19 (160) | G1(2) full (256) | G1(3) full (256)] = 672 bids
__global__ __launch_bounds__(512, 2) void gemm256_p1(
    const unsigned short* __restrict__ h0, const unsigned short* __restrict__ W2T0,
    const float* __restrict__ b20, unsigned short* __restrict__ obf0, const int* __restrict__ cnt0,
    const unsigned short* __restrict__ Abf,
    const unsigned short* __restrict__ W1T2, const float* __restrict__ b12,
    unsigned short* __restrict__ h2, const int* __restrict__ rl2, const int* __restrict__ cnt2,
    const unsigned short* __restrict__ W1T3, const float* __restrict__ b13,
    unsigned short* __restrict__ h3, const int* __restrict__ rl3, const int* __restrict__ cnt3) {
    extern __shared__ char lds_[];
    const int bid = blockIdx.x;
    if (bid < 160)      gemm_core<HID>(h0, W2T0, b20, obf0, HID, nullptr, cnt0, bid, 0, lds_);
    else if (bid < 416) gemm_core<IN_DIM>(Abf, W1T2, b12, h2, HID, rl2, cnt2, bid - 160, 0, lds_);
    else                gemm_core<IN_DIM>(Abf, W1T3, b13, h3, HID, rl3, cnt3, bid - 416, 0, lds_);
}
// D2: [G2(0) n20..31 (96) | G2(1) n0..19 (160)] = 256 bids
__global__ __launch_bounds__(512, 2) void gemm256_p2(
    const unsigned short* __restrict__ h0, const unsigned short* __restrict__ W2T0,
    const float* __restrict__ b20, unsigned short* __restrict__ obf0, const int* __restrict__ cnt0,
    const unsigned short* __restrict__ h1, const unsigned short* __restrict__ W2T1,
    const float* __restrict__ b21, unsigned short* __restrict__ obf1, const int* __restrict__ cnt1) {
    extern __shared__ char lds_[];
    const int bid = blockIdx.x;
    if (bid < 96) gemm_core<HID>(h0, W2T0, b20, obf0, HID, nullptr, cnt0, bid, 20, lds_);
    else          gemm_core<HID>(h1, W2T1, b21, obf1, HID, nullptr, cnt1, bid - 96, 0, lds_);
}
// D3: [G2(1) n20..31 (96) | G2(2) full (256) | G2(3) full (256)] = 608 bids
__global__ __launch_bounds__(512, 2) void gemm256_p3(
    const unsigned short* __restrict__ h1, const unsigned short* __restrict__ W2T1,
    const float* __restrict__ b21, unsigned short* __restrict__ obf1, const int* __restrict__ cnt1,
    const unsigned short* __restrict__ h2, const unsigned short* __restrict__ W2T2,
    const float* __restrict__ b22, unsigned short* __restrict__ obf2, const int* __restrict__ cnt2,
    const unsigned short* __restrict__ h3, const unsigned short* __restrict__ W2T3,
    const float* __restrict__ b23, unsigned short* __restrict__ obf3, const int* __restrict__ cnt3) {
    extern __shared__ char lds_[];
    const int bid = blockIdx.x;
    if (bid < 96)       gemm_core<HID>(h1, W2T1, b21, obf1, HID, nullptr, cnt1, bid, 20, lds_);
    else if (bid < 352) gemm_core<HID>(h2, W2T2, b22, obf2, HID, nullptr, cnt2, bid - 96, 0, lds_);
    else                gemm_core<HID>(h3, W2T3, b23, obf3, HID, nullptr, cnt3, bid - 352, 0, lds_);
}

// ---------------- Gram-Schmidt + gather: one wave per sample (compact obf via pos) ------------
__global__ __launch_bounds__(256, 1) void gs_kernel(
    const unsigned short* __restrict__ eo, const float* __restrict__ gval,
    const int* __restrict__ gidx, const int* __restrict__ pos,
    float* __restrict__ dout) {
    const int t = threadIdx.x, wave = t >> 6, lane = t & 63;
    const int n = blockIdx.x * 4 + wave;
    const int idx = gidx[n];
    const float g = gval[n];

    float v[32], b0[32], b1[32], b2[32];

    auto loadv = [&](float* dst, int e) {
        const size_t row = pos[(size_t)e * N_SAMP + n];
        const unsigned short* p = eo + ((size_t)e * N_SAMP + row) * HID + lane * 8;
        #pragma unroll
        for (int c = 0; c < 4; c++) {
            uint4 u = *(const uint4*)(p + c * 512);
            const unsigned short* us = (const unsigned short*)&u;
            #pragma unroll
            for (int j = 0; j < 8; j++) dst[c * 8 + j] = b2f(us[j]);
        }
    };
    auto wdot = [&](const float* x, const float* y) -> float {
        float s = 0.f;
        #pragma unroll
        for (int k = 0; k < 32; k++) s += x[k] * y[k];
        #pragma unroll
        for (int o = 32; o; o >>= 1) s += __shfl_xor(s, o);
        return s;
    };
    auto storev = [&](const float* b) {
        float* o = dout + (size_t)n * HID + lane * 8;
        #pragma unroll
        for (int c = 0; c < 4; c++) {
            float4 x0, x1;
            x0.x = g * b[c * 8 + 0]; x0.y = g * b[c * 8 + 1];
            x0.z = g * b[c * 8 + 2]; x0.w = g * b[c * 8 + 3];
            x1.x = g * b[c * 8 + 4]; x1.y = g * b[c * 8 + 5];
            x1.z = g * b[c * 8 + 6]; x1.w = g * b[c * 8 + 7];
            *(float4*)(o + c * 512) = x0;
            *(float4*)(o + c * 512 + 4) = x1;
        }
    };

    loadv(v, 0);
    float inv = 1.f / sqrtf(wdot(v, v));
    #pragma unroll
    for (int k = 0; k < 32; k++) b0[k] = v[k] * inv;
    if (idx == 0) { storev(b0); return; }
    loadv(v, 1);
    {
        float cc0 = wdot(v, b0);
        #pragma unroll
        for (int k = 0; k < 32; k++) v[k] -= cc0 * b0[k];
        inv = 1.f / sqrtf(wdot(v, v));
        #pragma unroll
        for (int k = 0; k < 32; k++) b1[k] = v[k] * inv;
    }
    if (idx == 1) { storev(b1); return; }
    loadv(v, 2);
    {
        float cc0 = wdot(v, b0);
        float cc1 = wdot(v, b1);
        #pragma unroll
        for (int k = 0; k < 32; k++) v[k] -= cc0 * b0[k] + cc1 * b1[k];
        inv = 1.f / sqrtf(wdot(v, v));
        #pragma unroll
        for (int k = 0; k < 32; k++) b2[k] = v[k] * inv;
    }
    if (idx == 2) { storev(b2); return; }
    loadv(v, 3);
    {
        float cc0 = wdot(v, b0);
        float cc1 = wdot(v, b1);
        float cc2 = wdot(v, b2);
        #pragma unroll
        for (int k = 0; k < 32; k++) v[k] -= cc0 * b0[k] + cc1 * b1[k] + cc2 * b2[k];
        inv = 1.f / sqrtf(wdot(v, v));
        #pragma unroll
        for (int k = 0; k < 32; k++) v[k] *= inv;
    }
    storev(v);
}

extern "C" void kernel_launch(void* const* d_in, const int* in_sizes, int n_in,
                              void* d_out, int out_size, void* d_ws, size_t ws_size,
                              hipStream_t stream) {
    const float* bb   = (const float*)d_in[0];
    const int*   task = (const int*)d_in[1];
    const float* temb = (const float*)d_in[2];
    const float* rm   = (const float*)d_in[3];
    const float* W1   = (const float*)d_in[4];
    const float* b1   = (const float*)d_in[5];
    const float* W2   = (const float*)d_in[6];
    const float* b2   = (const float*)d_in[7];
    float* out = (float*)d_out;
    char* ws = (char*)d_ws;

    const size_t lds_bytes = 131072;
    const size_t W1S = (size_t)IN_DIM * HID;
    const size_t W2S = (size_t)HID * HID;
    const size_t NEED_E = 277151760;           // plan E: n-split packed schedule
    const size_t NEED_C = 251986176;           // plan C (r12/r14 proven)
    const size_t NEED_B = 243597376;

    if (ws_size >= NEED_E) {
        // ===== Plan E: balanced packing, GEMM makespans 80+81+81+81 =====
        // D0:[G1(0)->h0|G1(1)->h1]  D1:[G2(0)n0-19|G1(2)|G1(3)]
        // D2:[G2(0)n20-31|G2(1)n0-19]  D3:[G2(1)n20-31|G2(2)|G2(3)]
        // h0 = obf[3] slot (first written by G2(3) in D3, after h0's last read in D2).
        unsigned short* obf  = (unsigned short*)(ws + 0);           // 128M [E][N][HID]
        unsigned short* h0   = obf + (size_t)3 * N_SAMP * HID;      // = obf[3] slot
        unsigned short* h1   = (unsigned short*)(ws + 134217728);   // 32M dedicated
        unsigned short* Abf  = (unsigned short*)(ws + 167772160);   // 16M (dead after D1)
        unsigned short* h2   = (unsigned short*)(ws + 184549376);   // 32M
        unsigned short* h3   = (unsigned short*)(ws + 218103808);   // 32M
        unsigned short* W1T  = (unsigned short*)(ws + 251658240);   // 8M rotating (2 experts)
        unsigned short* W2T  = (unsigned short*)(ws + 260046848);   // 16M (e0,e1)
        unsigned short* W2T23 = Abf;                                // e2,e3 after D1
        float* gv   = (float*)(ws + 276824064);
        int*   gi   = (int*)(ws + 276824064 + 32768);
        int*   list = (int*)(ws + 276824064 + 65536);
        int*   pos  = (int*)(ws + 276824064 + 196608);
        int*   cnt  = (int*)(ws + 276824064 + 327680);

        router_kernel<<<N_SAMP / 4, 256, 0, stream>>>(bb, task, temb, rm, Abf, gv, gi,
                                                      out + (size_t)N_SAMP * HID);
        compact_kernel<<<NE, 256, 0, stream>>>(gi, list, pos, cnt);
        transpose_conv<<<dim3(IN_DIM / 64, HID / 64, 2), 256, 0, stream>>>(
            W1, W1T, IN_DIM, HID, W1S, W1S);                       // W1T(0,1)
        transpose_conv<<<dim3(HID / 64, HID / 64, 2), 256, 0, stream>>>(
            W2, W2T, HID, HID, W2S, W2S);                          // W2T(0,1)

        // D0: [G1(0)->h0 | G1(1)->h1]
        gemm256_dual_g1g1<<<512, 512, lds_bytes, stream>>>(
            Abf, W1T, b1, h0, list, cnt,
            W1T + W1S, b1 + HID, h1, list + N_SAMP, cnt + 1);

        // W1T(2,3) into the rotating buffer (last read of (0,1) was D0)
        transpose_conv<<<dim3(IN_DIM / 64, HID / 64, 2), 256, 0, stream>>>(
            W1 + 2 * W1S, W1T, IN_DIM, HID, W1S, W1S);

        // D1: [G2(0) n0-19 | G1(2)->h2 | G1(3)->h3]
        gemm256_p1<<<672, 512, lds_bytes, stream>>>(
            h0, W2T, b2, obf, cnt,
            Abf, W1T, b1 + 2 * HID, h2, list + (size_t)2 * N_SAMP, cnt + 2,
            W1T + W1S, b1 + 3 * HID, h3, list + (size_t)3 * N_SAMP, cnt + 3);

        // W2T(2,3) -> dead Abf region (Abf's last read was in D1)
        transpose_conv<<<dim3(HID / 64, HID / 64, 2), 256, 0, stream>>>(
            W2 + 2 * W2S, W2T23, HID, HID, W2S, W2S);

        // D2: [G2(0) n20-31 | G2(1) n0-19]
        gemm256_p2<<<256, 512, lds_bytes, stream>>>(
            h0, W2T, b2, obf, cnt,
            h1, W2T + W2S, b2 + HID, obf + (size_t)1 * N_SAMP * HID, cnt + 1);

        // D3: [G2(1) n20-31 | G2(2) | G2(3)]
        gemm256_p3<<<608, 512, lds_bytes, stream>>>(
            h1, W2T + W2S, b2 + HID, obf + (size_t)1 * N_SAMP * HID, cnt + 1,
            h2, W2T23, b2 + 2 * HID, obf + (size_t)2 * N_SAMP * HID, cnt + 2,
            h3, W2T23 + W2S, b2 + 3 * HID, obf + (size_t)3 * N_SAMP * HID, cnt + 3);

        gs_kernel<<<N_SAMP / 4, 256, 0, stream>>>(obf, gv, gi, pos, out);
    } else if (ws_size >= NEED_B) {
        // ===== Plan C/B: r14 proven =====
        const bool planC = (ws_size >= NEED_C);
        unsigned short* obf  = (unsigned short*)(ws + 0);
        unsigned short* h0   = (unsigned short*)(ws + 33554432);    // = obf[1] slot
        unsigned short* h1   = (unsigned short*)(ws + 67108864);    // = obf[2] slot
        unsigned short* Abf  = (unsigned short*)(ws + 134217728);
        unsigned short* h2   = (unsigned short*)(ws + 150994944);
        unsigned short* h3   = (unsigned short*)(ws + 184549376);
        unsigned short* W1T  = (unsigned short*)(ws + 218103808);
        unsigned short* W2T  = (unsigned short*)(ws + 234881024);
        unsigned short* W2T23 = Abf;
        const size_t smallOfs = planC ? 251658240u : 243269632u;
        float* gv   = (float*)(ws + smallOfs);
        int*   gi   = (int*)(ws + smallOfs + 32768);
        int*   list = (int*)(ws + smallOfs + 65536);
        int*   pos  = (int*)(ws + smallOfs + 196608);
        int*   cnt  = (int*)(ws + smallOfs + 327680);

        router_kernel<<<N_SAMP / 4, 256, 0, stream>>>(bb, task, temb, rm, Abf, gv, gi,
                                                      out + (size_t)N_SAMP * HID);
        compact_kernel<<<NE, 256, 0, stream>>>(gi, list, pos, cnt);

        transpose_conv<<<dim3(IN_DIM / 64, HID / 64, NE), 256, 0, stream>>>(
            W1, W1T, IN_DIM, HID, W1S, W1S);
        if (planC) {
            transpose_conv<<<dim3(HID / 64, HID / 64, 2), 256, 0, stream>>>(
                W2, W2T, HID, HID, W2S, W2S);
        } else {
            transpose_conv<<<dim3(HID / 64, HID / 64, 1), 256, 0, stream>>>(
                W2, W2T, HID, HID, 0, 0);
        }

        gemm256_dual_g1g1<<<512, 512, lds_bytes, stream>>>(
            Abf, W1T, b1, h0, list, cnt,
            W1T + W1S, b1 + HID, h1, list + N_SAMP, cnt + 1);

        gemm256_dual<<<512, 512, lds_bytes, stream>>>(
            h0, W2T, b2, obf, cnt,
            Abf, W1T + 2 * W1S, b1 + 2 * HID, h2, list + (size_t)2 * N_SAMP, cnt + 2);

        if (!planC) {
            transpose_conv<<<dim3(HID / 64, HID / 64, 1), 256, 0, stream>>>(
                W2 + W2S, W2T, HID, HID, 0, 0);
        }
        const unsigned short* W2T1 = planC ? (W2T + W2S) : W2T;

        gemm256_dual<<<512, 512, lds_bytes, stream>>>(
            h1, W2T1, b2 + HID, obf + (size_t)1 * N_SAMP * HID, cnt + 1,
            Abf, W1T + 3 * W1S, b1 + 3 * HID, h3, list + (size_t)3 * N_SAMP, cnt + 3);

        transpose_conv<<<dim3(HID / 64, HID / 64, 2), 256, 0, stream>>>(
            W2 + 2 * W2S, W2T23, HID, HID, W2S, W2S);

        gemm256_dual_g2g2<<<512, 512, lds_bytes, stream>>>(
            h2, W2T23, b2 + 2 * HID, obf + (size_t)2 * N_SAMP * HID, cnt + 2,
            h3, W2T23 + W2S, b2 + 3 * HID, obf + (size_t)3 * N_SAMP * HID, cnt + 3);

        gs_kernel<<<N_SAMP / 4, 256, 0, stream>>>(obf, gv, gi, pos, out);
    } else {
        // ===== fallback: round-9 structure, ~197.5 MB (proven) =====
        unsigned short* obf  = (unsigned short*)(ws + 0);
        unsigned short* Abf  = (unsigned short*)(ws + 134217728);
        unsigned short* hbfA = (unsigned short*)(ws + 150994944);
        unsigned short* W1T  = (unsigned short*)(ws + 184549376);
        unsigned short* W2T  = (unsigned short*)(ws + 188743680);
        float*          gv   = (float*)(ws + 197132288);
        int*            gi   = (int*)(ws + 197165056);
        int*            list = (int*)(ws + 197197824);
        int*            pos  = (int*)(ws + 197328896);
        int*            cnt  = (int*)(ws + 197459968);
        unsigned short* hbfB = obf + (size_t)3 * N_SAMP * HID;
        auto hbf = [&](int e) { return (e & 1) ? hbfA : hbfB; };

        router_kernel<<<N_SAMP / 4, 256, 0, stream>>>(bb, task, temb, rm, Abf, gv, gi,
                                                      out + (size_t)N_SAMP * HID);
        compact_kernel<<<NE, 256, 0, stream>>>(gi, list, pos, cnt);

        transpose_conv<<<dim3(IN_DIM / 64, HID / 64, 1), 256, 0, stream>>>(
            W1, W1T, IN_DIM, HID, 0, 0);
        gemm256<IN_DIM><<<256, 512, lds_bytes, stream>>>(
            Abf, W1T, b1, hbf(0), HID, list, cnt);

        for (int e = 0; e < 3; ++e) {
            transpose_conv<<<dim3(HID / 64, HID / 64, 1), 256, 0, stream>>>(
                W2 + (size_t)e * W2S, W2T, HID, HID, 0, 0);
            transpose_conv<<<dim3(IN_DIM / 64, HID / 64, 1), 256, 0, stream>>>(
                W1 + (size_t)(e + 1) * W1S, W1T, IN_DIM, HID, 0, 0);
            gemm256_dual<<<512, 512, lds_bytes, stream>>>(
                hbf(e), W2T, b2 + (size_t)e * HID, obf + (size_t)e * N_SAMP * HID, cnt + e,
                Abf, W1T, b1 + (size_t)(e + 1) * HID, hbf(e + 1),
                list + (size_t)(e + 1) * N_SAMP, cnt + e + 1);
        }

        transpose_conv<<<dim3(HID / 64, HID / 64, 1), 256, 0, stream>>>(
            W2 + (size_t)3 * W2S, W2T, HID, HID, 0, 0);
        gemm256<HID><<<256, 512, lds_bytes, stream>>>(
            hbf(3), W2T, b2 + (size_t)3 * HID, obf + (size_t)3 * N_SAMP * HID, HID,
            nullptr, cnt + 3);

        gs_kernel<<<N_SAMP / 4, 256, 0, stream>>>(obf, gv, gi, pos, out);
    }
}